// Round 13
// baseline (226.744 us; speedup 1.0000x reference)
//
#include <hip/hip_runtime.h>
#include <hip/hip_bf16.h>
#include <math.h>

// GAT forward, N=4096, nfeat=512, nhid=64, nheads=8, nout=56, f32 in/out.
// R13 vs R12 (R12: 220us, absmax identical with w hi-only; attn-L1 73.5us
// GRID-capped at 16 waves/CU - occ 32%, VALU 59%, MFMA 9%):
//  - attn13: 32-row blocks (i-split, NOT j-split -> pO unchanged): 4 waves =
//    2 rowgroups x 2 ks-halves, each wave 16 rows x 32-j k-slice (half the
//    w-gen of R12 per wave). Grid 128x16 = 2048 blocks = 8 blk/CU x 4 waves
//    = 32 waves/CU ceiling (was 16). Cross-ks-half acc/den combined via LDS
//    after the loop (R8-proven pattern, staging bufs reused).
//  - numerics byte-identical to R12 (w hi-only, rounded-consistent den);
//    only den summation order differs.
//  - prep/gemm/mid/fink2 unchanged from R12.
// Workspace ~25 MB.

#define GN 4096
#define GNH 8
#define LOG2E 1.4426950408889634f

typedef __bf16 bf16x8 __attribute__((ext_vector_type(8)));
typedef float f32x4 __attribute__((ext_vector_type(4)));

#if defined(__has_builtin)
#if __has_builtin(__builtin_amdgcn_exp2f)
#define FAST_EXP2(x) __builtin_amdgcn_exp2f(x)
#endif
#if __has_builtin(__builtin_amdgcn_perm)
#define FAST_PERM(a, b, s) __builtin_amdgcn_perm((a), (b), (s))
#endif
#endif
#ifndef FAST_EXP2
#define FAST_EXP2(x) __expf((x)*0.6931471805599453f)
#endif
#ifndef FAST_PERM
__device__ inline unsigned FAST_PERM(unsigned a, unsigned b, unsigned) {
    return (a & 0xFFFF0000u) | (b >> 16);
}
#endif

// round-half-up hi/lo split + pack two values into (hi-pack, lo-pack) u32s
__device__ inline void split_pack2(float w0, float w1, unsigned& hp, unsigned& lp) {
    unsigned u0 = __float_as_uint(w0) + 0x8000u;
    unsigned u1 = __float_as_uint(w1) + 0x8000u;
    float l0 = w0 - __uint_as_float(u0 & 0xFFFF0000u);
    float l1 = w1 - __uint_as_float(u1 & 0xFFFF0000u);
    hp = FAST_PERM(u1, u0, 0x07060302u);
    lp = FAST_PERM(__float_as_uint(l1), __float_as_uint(l0), 0x07060302u);
}

// round-half-up hi only, packed pair
__device__ inline unsigned hi_pack2(float w0, float w1) {
    unsigned u0 = __float_as_uint(w0) + 0x8000u;
    unsigned u1 = __float_as_uint(w1) + 0x8000u;
    return FAST_PERM(u1, u0, 0x07060302u);
}

// Fused prep:
//  [0,16384)      pack_adj  (bitmask)
//  [16384,17408)  conv_x    -> swizzled x image (hi/lo), tiles [itile*8+kt]
//  [17408,17472)  conv_wt   -> swizzled W^T image (hi/lo), tiles [head*8+kt]
// Image unit (m, c) at shorts offset m*64 + ((c^(m&7))*8), elems k = c*8+q.
__global__ __launch_bounds__(256) void prep(const int* __restrict__ adj,
                                            const float* __restrict__ x,
                                            const float* __restrict__ Ws,
                                            unsigned long long* __restrict__ adjb,
                                            unsigned short* __restrict__ xh,
                                            unsigned short* __restrict__ xl,
                                            unsigned short* __restrict__ wth,
                                            unsigned short* __restrict__ wtl) {
    const int b = blockIdx.x;
    const int tid = threadIdx.x;
    if (b < 16384) {
        const int wv = tid >> 6, lane = tid & 63;
        const size_t ebase = ((size_t)b * 4 + wv) * 256;
        unsigned long long m[4];
        #pragma unroll
        for (int e = 0; e < 4; ++e)
            m[e] = __ballot(adj[ebase + e * 64 + lane] > 0);
        if (lane == 0) {
            #pragma unroll
            for (int e = 0; e < 4; ++e) adjb[(ebase >> 6) + e] = m[e];
        }
    } else if (b < 17408) {
        int gid = (b - 16384) * 256 + tid;           // over 4096 rows x 64 units
        int i = gid >> 6, c64 = gid & 63;
        const float* xp = x + (size_t)i * 512 + c64 * 8;
        float4 a = *(const float4*)xp;
        float4 v = *(const float4*)(xp + 4);
        unsigned hp[4], lp[4];
        split_pack2(a.x, a.y, hp[0], lp[0]);
        split_pack2(a.z, a.w, hp[1], lp[1]);
        split_pack2(v.x, v.y, hp[2], lp[2]);
        split_pack2(v.z, v.w, hp[3], lp[3]);
        int il = i & 63, kt = c64 >> 3, c = c64 & 7;
        size_t base = ((size_t)(i >> 6) * 8 + kt) * 4096 + il * 64 + ((c ^ (il & 7)) * 8);
        *(uint4*)&xh[base] = *(uint4*)hp;
        *(uint4*)&xl[base] = *(uint4*)lp;
    } else {
        __shared__ float t[64][65];
        int b2 = b - 17408;                          // head*8 + kt
        int head = b2 >> 3, k0 = (b2 & 7) * 64;
        #pragma unroll
        for (int it = 0; it < 4; ++it) {
            int e = (tid + it * 256) * 4;            // over 64k x 64f
            int kl = e >> 6, f4 = e & 63;
            float4 v = *(const float4*)&Ws[((size_t)head * 512 + k0 + kl) * 64 + f4];
            t[f4 + 0][kl] = v.x; t[f4 + 1][kl] = v.y;
            t[f4 + 2][kl] = v.z; t[f4 + 3][kl] = v.w;
        }
        __syncthreads();
        int f = tid >> 2;
        #pragma unroll
        for (int p = 0; p < 2; ++p) {
            int c = (tid & 3) * 2 + p;
            unsigned hp[4], lp[4];
            #pragma unroll
            for (int pp = 0; pp < 4; ++pp)
                split_pack2(t[f][c * 8 + 2 * pp], t[f][c * 8 + 2 * pp + 1], hp[pp], lp[pp]);
            size_t base = (size_t)b2 * 4096 + f * 64 + ((c ^ (f & 7)) * 8);
            *(uint4*)&wth[base] = *(uint4*)hp;
            *(uint4*)&wtl[base] = *(uint4*)lp;
        }
    }
}

// h = x @ Ws[head] (full 3-product split), m97-style staging. Epilogue emits
// hi-only swizzled h image + s1L/s2L. grid (8 heads, 64 itiles).
__global__ __launch_bounds__(256) void gemm_fused(const unsigned short* __restrict__ xh,
                                                  const unsigned short* __restrict__ xl,
                                                  const unsigned short* __restrict__ wth,
                                                  const unsigned short* __restrict__ wtl,
                                                  const float* __restrict__ As,
                                                  unsigned short* __restrict__ imgh,
                                                  float* __restrict__ s1L,
                                                  float* __restrict__ s2L) {
    __shared__ __align__(16) unsigned short lds[2][4][4096];  // 64 KB: [buf][xh,xl,wh,wl]
    const int tid = threadIdx.x;
    const int head = blockIdx.x;
    const int itile = blockIdx.y;
    const int i0 = itile * 64;
    const unsigned short* srcs[4] = {xh + (size_t)itile * 8 * 4096,
                                     xl + (size_t)itile * 8 * 4096,
                                     wth + (size_t)head * 8 * 4096,
                                     wtl + (size_t)head * 8 * 4096};
    const int lane = tid & 63, wv_ = tid >> 6;
    const int mi = (wv_ & 1) * 32, fi = (wv_ >> 1) * 32;
    const int row = lane & 15, quad = lane >> 4;
    f32x4 acc[2][2] = {};

    #define GSTAGE(buf, kt)                                                                \
        do {                                                                               \
            _Pragma("unroll")                                                              \
            for (int q_ = 0; q_ < 4; ++q_) {                                               \
                const unsigned short* s_ = srcs[q_] + (size_t)(kt) * 4096;                 \
                _Pragma("unroll")                                                          \
                for (int c_ = 0; c_ < 2; ++c_)                                             \
                    __builtin_amdgcn_global_load_lds(                                      \
                        (const __attribute__((address_space(1))) unsigned int*)(s_ + c_ * 2048 + tid * 8), \
                        (__attribute__((address_space(3))) unsigned int*)&lds[buf][q_][c_ * 2048 + tid * 8], \
                        16, 0, 0);                                                         \
            }                                                                              \
        } while (0)

    GSTAGE(0, 0);
    for (int kt = 0; kt < 8; ++kt) {
        __syncthreads();                             // drains loads into buf cur
        const int cur = kt & 1;
        if (kt + 1 < 8) GSTAGE(cur ^ 1, kt + 1);
        #pragma unroll
        for (int ks = 0; ks < 2; ++ks) {
            bf16x8 ah[2], al[2], bh[2], bl[2];
            #pragma unroll
            for (int t = 0; t < 2; ++t) {
                const int m_ = mi + t * 16 + row;
                const int offa = m_ * 64 + (((ks * 4 + quad) ^ (m_ & 7)) * 8);
                ah[t] = *(const bf16x8*)&lds[cur][0][offa];
                al[t] = *(const bf16x8*)&lds[cur][1][offa];
                const int f_ = fi + t * 16 + row;
                const int offb = f_ * 64 + (((ks * 4 + quad) ^ (f_ & 7)) * 8);
                bh[t] = *(const bf16x8*)&lds[cur][2][offb];
                bl[t] = *(const bf16x8*)&lds[cur][3][offb];
            }
            #pragma unroll
            for (int mt = 0; mt < 2; ++mt)
                #pragma unroll
                for (int nt = 0; nt < 2; ++nt) {
                    acc[mt][nt] = __builtin_amdgcn_mfma_f32_16x16x32_bf16(ah[mt], bh[nt], acc[mt][nt], 0, 0, 0);
                    acc[mt][nt] = __builtin_amdgcn_mfma_f32_16x16x32_bf16(al[mt], bh[nt], acc[mt][nt], 0, 0, 0);
                    acc[mt][nt] = __builtin_amdgcn_mfma_f32_16x16x32_bf16(ah[mt], bl[nt], acc[mt][nt], 0, 0, 0);
                }
        }
    }
    #undef GSTAGE
    // ---- fused epilogue ----
    __syncthreads();
    float* ht = (float*)&lds[0][0][0];               // 64 x 68 f32 (17.4 KB, fits)
    #pragma unroll
    for (int mt = 0; mt < 2; ++mt)
        #pragma unroll
        for (int nt = 0; nt < 2; ++nt)
            #pragma unroll
            for (int r = 0; r < 4; ++r)
                ht[(mi + mt * 16 + quad * 4 + r) * 68 + fi + nt * 16 + row] = acc[mt][nt][r];
    __syncthreads();
    {   // s1/s2 (pre-scaled by log2e): thread t -> row t>>2, seg (t&3)*16
        const int rrow = tid >> 2, seg = (tid & 3) * 16;
        const float* ah = As + head * 128;
        float p1 = 0.f, p2 = 0.f;
        #pragma unroll
        for (int c = 0; c < 16; ++c) {
            float v = ht[rrow * 68 + seg + c];
            p1 += v * ah[seg + c];
            p2 += v * ah[64 + seg + c];
        }
        p1 += __shfl_xor(p1, 1); p1 += __shfl_xor(p1, 2);
        p2 += __shfl_xor(p2, 1); p2 += __shfl_xor(p2, 2);
        if ((tid & 3) == 0) {
            s1L[head * GN + i0 + rrow] = p1 * LOG2E;
            s2L[head * GN + i0 + rrow] = p2 * LOG2E;
        }
    }
    {   // swizzled image emit (hi only)
        const int f = tid >> 2;
        size_t base = ((size_t)head * 64 + itile) * 4096 + (size_t)f * 64;
        #pragma unroll
        for (int p = 0; p < 2; ++p) {
            int c = (tid & 3) * 2 + p;
            unsigned hp[4];
            #pragma unroll
            for (int pp = 0; pp < 4; ++pp)
                hp[pp] = hi_pack2(ht[(c * 8 + 2 * pp) * 68 + f], ht[(c * 8 + 2 * pp + 1) * 68 + f]);
            int off = (c ^ (f & 7)) * 8;
            *(uint4*)&imgh[base + off] = *(uint4*)hp;
        }
    }
}

// Fused masked-softmax attention; w HI-ONLY (rounded-consistent den), h image
// HI-ONLY. 32-row blocks: 4 waves = 2 rowgroups x 2 ks-halves; each wave
// 16 rows x 32-j k-slice, nt=4. Cross-half combine via LDS (R8 pattern).
// grid (128 i-blocks, GNH*NCHUNK or NCHUNK).
template <int NCHUNK>
__global__ __launch_bounds__(256, 8) void attn13(const unsigned short* __restrict__ imgh,
                                                 const float* __restrict__ s1g,
                                                 const float* __restrict__ s2g,
                                                 const unsigned* __restrict__ adj32,
                                                 float* __restrict__ pO,
                                                 float* __restrict__ pd) {
    __shared__ __align__(16) unsigned short hb[2][4096];   // [buf][hi, swizzled 64x64]
    const int tid = threadIdx.x;
    const int lane = tid & 63, wv = tid >> 6;
    const int rowgrp = wv >> 1, jhalf = wv & 1;
    const int row = lane & 15, quad = lane >> 4;
    const int head = blockIdx.y / NCHUNK;
    const int chunk = blockIdx.y % NCHUNK;
    const int i0 = blockIdx.x * 32;
    const int jb = chunk * (GN / NCHUNK);
    const int njt = (GN / NCHUNK) / 64;
    const int jt0 = jb >> 6;
    const unsigned short* ih = imgh + (size_t)head * (64 * GN);
    const float* s2h = s2g + head * GN;
    const int gr = i0 + rowgrp * 16 + row;
    const float s1v = s1g[head * GN + gr];
    const unsigned* adjr = adj32 + (size_t)gr * 128 + jt0 * 2 + jhalf;
    const int kb = jhalf * 32 + quad * 8;            // j-offset of this lane's k-frag

    f32x4 acc[4] = {};
    float den = 0.f;

    #define STAGE(buf, T)                                                                  \
        do {                                                                               \
            const unsigned short* gh_ = ih + (size_t)(T) * 4096;                           \
            _Pragma("unroll")                                                              \
            for (int c_ = 0; c_ < 2; ++c_)                                                 \
                __builtin_amdgcn_global_load_lds(                                          \
                    (const __attribute__((address_space(1))) unsigned int*)(gh_ + c_ * 2048 + tid * 8), \
                    (__attribute__((address_space(3))) unsigned int*)&hb[buf][c_ * 2048 + tid * 8],     \
                    16, 0, 0);                                                             \
        } while (0)

    STAGE(0, jt0);
    for (int jt = 0; jt < njt; ++jt) {
        __syncthreads();                             // drains loads into buf cur
        const int cur = jt & 1;
        if (jt + 1 < njt) STAGE(cur ^ 1, jt0 + jt + 1);
        const int j0 = jb + jt * 64;
        const unsigned w32 = adjr[jt * 2];
        const unsigned bits = (w32 >> (quad * 8)) & 0xFFu;
        float4 sa = *(const float4*)&s2h[j0 + kb];
        float4 sb = *(const float4*)&s2h[j0 + kb + 4];
        const float s2v[8] = {sa.x, sa.y, sa.z, sa.w, sb.x, sb.y, sb.z, sb.w};
        union { unsigned u[4]; bf16x8 v; } hfr;
        #pragma unroll
        for (int p = 0; p < 4; ++p) {
            float m0 = (float)((bits >> (2 * p)) & 1u);
            float m1 = (float)((bits >> (2 * p + 1)) & 1u);
            float t0 = s1v + s2v[2 * p];
            float t1 = s1v + s2v[2 * p + 1];
            float w0 = FAST_EXP2(fmaxf(t0, 0.2f * t0)) * m0;
            float w1 = FAST_EXP2(fmaxf(t1, 0.2f * t1)) * m1;
            unsigned u0 = __float_as_uint(w0) + 0x8000u;
            unsigned u1 = __float_as_uint(w1) + 0x8000u;
            den += __uint_as_float(u0 & 0xFFFF0000u) + __uint_as_float(u1 & 0xFFFF0000u);
            hfr.u[p] = FAST_PERM(u1, u0, 0x07060302u);
        }
        #pragma unroll
        for (int nt = 0; nt < 4; ++nt) {
            const int f = nt * 16 + row;
            const int off = f * 64 + (((jhalf * 4 + quad) ^ (f & 7)) * 8);
            bf16x8 bh = *(const bf16x8*)&hb[cur][off];
            acc[nt] = __builtin_amdgcn_mfma_f32_16x16x32_bf16(hfr.v, bh, acc[nt], 0, 0, 0);
        }
    }
    #undef STAGE
    // row denominators within this ks-half: lanes {l, l^16, l^32, l^48} share a row
    den += __shfl_xor(den, 16);
    den += __shfl_xor(den, 32);
    // cross-half combine via LDS (staging buffers dead now)
    __syncthreads();
    float* cb = (float*)&hb[0][0];                   // 2 rowgrp x 4 nt x 256 f32 = 8 KB
    float* db = cb + 2048;                           // 32 f32
    if (jhalf == 1) {
        #pragma unroll
        for (int nt = 0; nt < 4; ++nt)
            *(f32x4*)&cb[(rowgrp * 4 + nt) * 256 + lane * 4] = acc[nt];
        if (quad == 0) db[rowgrp * 16 + row] = den;
    }
    __syncthreads();
    if (jhalf == 0) {
        float dtot = den + db[rowgrp * 16 + row];
        float* o = pO + (size_t)blockIdx.y * (GN * 64);
        #pragma unroll
        for (int nt = 0; nt < 4; ++nt) {
            f32x4 v = acc[nt] + *(const f32x4*)&cb[(rowgrp * 4 + nt) * 256 + lane * 4];
            #pragma unroll
            for (int r = 0; r < 4; ++r) {
                const int grow = i0 + rowgrp * 16 + quad * 4 + r;
                o[(size_t)grow * 64 + nt * 16 + row] = v[r];
            }
        }
        if (lane < 16) pd[blockIdx.y * GN + i0 + rowgrp * 16 + lane] = dtot;
    }
}

// Fused zred + l2prep, 16 rows/block (256 blocks): combine 2-chunk L1
// partials -> z (LDS) -> h2 = z @ W_out -> s1b/s2b + hi-only image.
__global__ __launch_bounds__(256) void mid(const float* __restrict__ pO,
                                           const float* __restrict__ pd,
                                           const float* __restrict__ Wo,
                                           const float* __restrict__ ao,
                                           unsigned short* __restrict__ img2h,
                                           float* __restrict__ s1bL,
                                           float* __restrict__ s2bL) {
    __shared__ __align__(16) float zt[16][68];
    __shared__ float Wl[64 * 57];
    __shared__ float invd[8][16];
    const int tid = threadIdx.x;
    const int i0 = blockIdx.x * 16;
    for (int idx = tid; idx < 64 * 56; idx += 256) {
        int k = idx / 56, c = idx - k * 56;
        Wl[k * 57 + c] = Wo[idx];
    }
    if (tid < 128) {
        int hd = tid >> 4, r = tid & 15;
        invd[hd][r] = 1.f / (pd[(2 * hd) * GN + i0 + r] + pd[(2 * hd + 1) * GN + i0 + r]);
    }
    __syncthreads();
    #pragma unroll
    for (int it = 0; it < 4; ++it) {                 // z fill: 16x64 elems
        int e = it * 256 + tid;
        int r = e >> 6, f = e & 63;
        size_t base = (size_t)(i0 + r) * 64 + f;
        float s = 0.f;
        #pragma unroll
        for (int hd = 0; hd < GNH; ++hd) {
            float o = pO[(size_t)(2 * hd) * (GN * 64) + base] +
                      pO[(size_t)(2 * hd + 1) * (GN * 64) + base];
            float v = o * invd[hd][r];
            s += v > 0.f ? v : FAST_EXP2(v * LOG2E) - 1.f;
        }
        zt[r][f] = s * 0.125f;
    }
    __syncthreads();
    const int rrow = tid >> 4, cseg = (tid & 15) * 4;
    float hreg[4] = {0.f, 0.f, 0.f, 0.f};
    for (int k0 = 0; k0 < 64; k0 += 4) {
        float4 zv = *(const float4*)&zt[rrow][k0];
        #pragma unroll
        for (int c = 0; c < 4; ++c) {
            int col = cseg + c;
            if (col < 56)
                hreg[c] += zv.x * Wl[k0 * 57 + col] + zv.y * Wl[(k0 + 1) * 57 + col] +
                           zv.z * Wl[(k0 + 2) * 57 + col] + zv.w * Wl[(k0 + 3) * 57 + col];
        }
    }
    {   // s1b/s2b (pre-scaled by log2e); reduce across 16 threads of the row
        float p1 = 0.f, p2 = 0.f;
        #pragma unroll
        for (int c = 0; c < 4; ++c) {
            int col = cseg + c;
            if (col < 56) {
                p1 += hreg[c] * ao[col];
                p2 += hreg[c] * ao[56 + col];
            }
        }
        p1 += __shfl_xor(p1, 1); p1 += __shfl_xor(p1, 2);
        p1 += __shfl_xor(p1, 4); p1 += __shfl_xor(p1, 8);
        p2 += __shfl_xor(p2, 1); p2 += __shfl_xor(p2, 2);
        p2 += __shfl_xor(p2, 4); p2 += __shfl_xor(p2, 8);
        if ((tid & 15) == 0) {
            s1bL[i0 + rrow] = p1 * LOG2E;
            s2bL[i0 + rrow] = p2 * LOG2E;
        }
    }
    __syncthreads();
    #pragma unroll
    for (int c = 0; c < 4; ++c) zt[rrow][cseg + c] = (cseg + c < 56) ? hreg[c] : 0.f;
    __syncthreads();
    if (tid < 128) {                                 // img emit: 64 f x 2 c-units
        const int jt = i0 >> 6;
        const int cbase = (i0 & 63) >> 3;
        const int f = tid >> 1, c = cbase + (tid & 1);
        const int lr = (tid & 1) * 8;
        unsigned hp[4];
        #pragma unroll
        for (int pp = 0; pp < 4; ++pp)
            hp[pp] = hi_pack2(zt[lr + 2 * pp][f], zt[lr + 2 * pp + 1][f]);
        size_t base = (size_t)jt * 4096 + f * 64 + ((c ^ (f & 7)) * 8);
        *(uint4*)&img2h[base] = *(uint4*)hp;
    }
}

// combine 16 j-chunk partials, /denom, elu, softmax(56) -> out
__global__ __launch_bounds__(256) void fink2(const float* __restrict__ pO,
                                             const float* __restrict__ pd,
                                             float* __restrict__ out) {
    const int lane = threadIdx.x & 63;
    const int w = threadIdx.x >> 6;
    const int i = blockIdx.x * 4 + w;
    float o = 0.f, d = 0.f;
    #pragma unroll
    for (int c = 0; c < 16; ++c) d += pd[c * GN + i];
    if (lane < 56) {
        #pragma unroll
        for (int c = 0; c < 16; ++c) o += pO[(size_t)c * (GN * 64) + (size_t)i * 64 + lane];
    }
    float v = -1e30f;
    if (lane < 56) {
        float t = o / d;
        v = t > 0.f ? t : expm1f(t);
    }
    float m = v;
    #pragma unroll
    for (int off = 32; off; off >>= 1) m = fmaxf(m, __shfl_down(m, off));
    m = __shfl(m, 0);
    float p = (lane < 56) ? __expf(v - m) : 0.f;
    float s = p;
    #pragma unroll
    for (int off = 32; off; off >>= 1) s += __shfl_down(s, off);
    s = __shfl(s, 0);
    if (lane < 56) out[(size_t)i * 56 + lane] = p / s;
}

extern "C" void kernel_launch(void* const* d_in, const int* in_sizes, int n_in,
                              void* d_out, int out_size, void* d_ws, size_t ws_size,
                              hipStream_t stream) {
    const float* x    = (const float*)d_in[0];
    const int*   adj  = (const int*)d_in[1];
    const float* Ws   = (const float*)d_in[2];
    const float* As   = (const float*)d_in[3];
    const float* Wo   = (const float*)d_in[4];
    const float* ao   = (const float*)d_in[5];
    float* out = (float*)d_out;

    char* ws = (char*)d_ws;
    unsigned long long* adjb = (unsigned long long*)(ws + 0);           // 2 MB
    unsigned short* img1h = (unsigned short*)(ws + 2097152);            // 4 MB
    float* pO    = (float*)(ws + 6291456);                              // 16 MB (16 slices)
    unsigned short* x_hi = (unsigned short*)(ws + 6291456);             // 4 MB (alias pO, pre-gemm)
    unsigned short* x_lo = (unsigned short*)(ws + 10485760);            // 4 MB (alias pO, pre-gemm)
    float* pd    = (float*)(ws + 23068672);                             // 256 KB (shared L1/L2)
    float* s1L   = (float*)(ws + 23330816);                             // 128 KB
    float* s2L   = (float*)(ws + 23461888);                             // 128 KB
    float* s1bL  = (float*)(ws + 23592960);                             // 16 KB
    float* s2bL  = (float*)(ws + 23609344);                             // 16 KB
    unsigned short* img2h = (unsigned short*)(ws + 23625728);           // 512 KB
    unsigned short* WT_hi = (unsigned short*)(ws + 24150016);           // 512 KB
    unsigned short* WT_lo = (unsigned short*)(ws + 24674304);           // 512 KB
    // total 25198592 B ~= 24 MB

    prep<<<17472, 256, 0, stream>>>(adj, x, Ws, adjb, x_hi, x_lo, WT_hi, WT_lo);
    gemm_fused<<<dim3(8, 64), 256, 0, stream>>>(x_hi, x_lo, WT_hi, WT_lo, As,
                                                img1h, s1L, s2L);
    attn13<2><<<dim3(128, 16), 256, 0, stream>>>(img1h, s1L, s2L,
                                                 (const unsigned*)adjb, pO, pd);
    mid<<<256, 256, 0, stream>>>(pO, pd, Wo, ao, img2h, s1bL, s2bL);
    attn13<16><<<dim3(128, 16), 256, 0, stream>>>(img2h, s1bL, s2bL,
                                                  (const unsigned*)adjb, pO, pd);
    fink2<<<1024, 256, 0, stream>>>(pO, pd, out);
}

// Round 14
// 217.528 us; speedup vs baseline: 1.0424x; 1.0424x over previous
//
#include <hip/hip_runtime.h>
#include <hip/hip_bf16.h>
#include <math.h>

// GAT forward, N=4096, nfeat=512, nhid=64, nheads=8, nout=56, f32 in/out.
// R14 = R12 (best, 220.3us) + ONE change: in attn10's loop, the s2/adj
// register loads are issued BEFORE STAGE(next). vmcnt is in-order, so in R12
// the wait on s2 also drained the just-issued next-tile global_load_lds --
// every iteration serialized compute behind next-tile staging (R7's failure
// mode, latent in all attn shells; R13 proved occupancy was NOT the limit).
// With loads-first, s2's wait leaves staging in flight; staging drains at the
// post-compute barrier = true double buffering. Math bit-identical.
// R13's i-split (2x staging, LDS combine) reverted.
// Workspace ~25 MB.

#define GN 4096
#define GNH 8
#define LOG2E 1.4426950408889634f

typedef __bf16 bf16x8 __attribute__((ext_vector_type(8)));
typedef float f32x4 __attribute__((ext_vector_type(4)));

#if defined(__has_builtin)
#if __has_builtin(__builtin_amdgcn_exp2f)
#define FAST_EXP2(x) __builtin_amdgcn_exp2f(x)
#endif
#if __has_builtin(__builtin_amdgcn_perm)
#define FAST_PERM(a, b, s) __builtin_amdgcn_perm((a), (b), (s))
#endif
#endif
#ifndef FAST_EXP2
#define FAST_EXP2(x) __expf((x)*0.6931471805599453f)
#endif
#ifndef FAST_PERM
__device__ inline unsigned FAST_PERM(unsigned a, unsigned b, unsigned) {
    return (a & 0xFFFF0000u) | (b >> 16);
}
#endif

// round-half-up hi/lo split + pack two values into (hi-pack, lo-pack) u32s
__device__ inline void split_pack2(float w0, float w1, unsigned& hp, unsigned& lp) {
    unsigned u0 = __float_as_uint(w0) + 0x8000u;
    unsigned u1 = __float_as_uint(w1) + 0x8000u;
    float l0 = w0 - __uint_as_float(u0 & 0xFFFF0000u);
    float l1 = w1 - __uint_as_float(u1 & 0xFFFF0000u);
    hp = FAST_PERM(u1, u0, 0x07060302u);
    lp = FAST_PERM(__float_as_uint(l1), __float_as_uint(l0), 0x07060302u);
}

// round-half-up hi only, packed pair
__device__ inline unsigned hi_pack2(float w0, float w1) {
    unsigned u0 = __float_as_uint(w0) + 0x8000u;
    unsigned u1 = __float_as_uint(w1) + 0x8000u;
    return FAST_PERM(u1, u0, 0x07060302u);
}

// Fused prep:
//  [0,16384)      pack_adj  (bitmask)
//  [16384,17408)  conv_x    -> swizzled x image (hi/lo), tiles [itile*8+kt]
//  [17408,17472)  conv_wt   -> swizzled W^T image (hi/lo), tiles [head*8+kt]
// Image unit (m, c) at shorts offset m*64 + ((c^(m&7))*8), elems k = c*8+q.
__global__ __launch_bounds__(256) void prep(const int* __restrict__ adj,
                                            const float* __restrict__ x,
                                            const float* __restrict__ Ws,
                                            unsigned long long* __restrict__ adjb,
                                            unsigned short* __restrict__ xh,
                                            unsigned short* __restrict__ xl,
                                            unsigned short* __restrict__ wth,
                                            unsigned short* __restrict__ wtl) {
    const int b = blockIdx.x;
    const int tid = threadIdx.x;
    if (b < 16384) {
        const int wv = tid >> 6, lane = tid & 63;
        const size_t ebase = ((size_t)b * 4 + wv) * 256;
        unsigned long long m[4];
        #pragma unroll
        for (int e = 0; e < 4; ++e)
            m[e] = __ballot(adj[ebase + e * 64 + lane] > 0);
        if (lane == 0) {
            #pragma unroll
            for (int e = 0; e < 4; ++e) adjb[(ebase >> 6) + e] = m[e];
        }
    } else if (b < 17408) {
        int gid = (b - 16384) * 256 + tid;           // over 4096 rows x 64 units
        int i = gid >> 6, c64 = gid & 63;
        const float* xp = x + (size_t)i * 512 + c64 * 8;
        float4 a = *(const float4*)xp;
        float4 v = *(const float4*)(xp + 4);
        unsigned hp[4], lp[4];
        split_pack2(a.x, a.y, hp[0], lp[0]);
        split_pack2(a.z, a.w, hp[1], lp[1]);
        split_pack2(v.x, v.y, hp[2], lp[2]);
        split_pack2(v.z, v.w, hp[3], lp[3]);
        int il = i & 63, kt = c64 >> 3, c = c64 & 7;
        size_t base = ((size_t)(i >> 6) * 8 + kt) * 4096 + il * 64 + ((c ^ (il & 7)) * 8);
        *(uint4*)&xh[base] = *(uint4*)hp;
        *(uint4*)&xl[base] = *(uint4*)lp;
    } else {
        __shared__ float t[64][65];
        int b2 = b - 17408;                          // head*8 + kt
        int head = b2 >> 3, k0 = (b2 & 7) * 64;
        #pragma unroll
        for (int it = 0; it < 4; ++it) {
            int e = (tid + it * 256) * 4;            // over 64k x 64f
            int kl = e >> 6, f4 = e & 63;
            float4 v = *(const float4*)&Ws[((size_t)head * 512 + k0 + kl) * 64 + f4];
            t[f4 + 0][kl] = v.x; t[f4 + 1][kl] = v.y;
            t[f4 + 2][kl] = v.z; t[f4 + 3][kl] = v.w;
        }
        __syncthreads();
        int f = tid >> 2;
        #pragma unroll
        for (int p = 0; p < 2; ++p) {
            int c = (tid & 3) * 2 + p;
            unsigned hp[4], lp[4];
            #pragma unroll
            for (int pp = 0; pp < 4; ++pp)
                split_pack2(t[f][c * 8 + 2 * pp], t[f][c * 8 + 2 * pp + 1], hp[pp], lp[pp]);
            size_t base = (size_t)b2 * 4096 + f * 64 + ((c ^ (f & 7)) * 8);
            *(uint4*)&wth[base] = *(uint4*)hp;
            *(uint4*)&wtl[base] = *(uint4*)lp;
        }
    }
}

// h = x @ Ws[head] (full 3-product split), m97-style staging. Epilogue emits
// hi-only swizzled h image + s1L/s2L. grid (8 heads, 64 itiles).
__global__ __launch_bounds__(256) void gemm_fused(const unsigned short* __restrict__ xh,
                                                  const unsigned short* __restrict__ xl,
                                                  const unsigned short* __restrict__ wth,
                                                  const unsigned short* __restrict__ wtl,
                                                  const float* __restrict__ As,
                                                  unsigned short* __restrict__ imgh,
                                                  float* __restrict__ s1L,
                                                  float* __restrict__ s2L) {
    __shared__ __align__(16) unsigned short lds[2][4][4096];  // 64 KB: [buf][xh,xl,wh,wl]
    const int tid = threadIdx.x;
    const int head = blockIdx.x;
    const int itile = blockIdx.y;
    const int i0 = itile * 64;
    const unsigned short* srcs[4] = {xh + (size_t)itile * 8 * 4096,
                                     xl + (size_t)itile * 8 * 4096,
                                     wth + (size_t)head * 8 * 4096,
                                     wtl + (size_t)head * 8 * 4096};
    const int lane = tid & 63, wv_ = tid >> 6;
    const int mi = (wv_ & 1) * 32, fi = (wv_ >> 1) * 32;
    const int row = lane & 15, quad = lane >> 4;
    f32x4 acc[2][2] = {};

    #define GSTAGE(buf, kt)                                                                \
        do {                                                                               \
            _Pragma("unroll")                                                              \
            for (int q_ = 0; q_ < 4; ++q_) {                                               \
                const unsigned short* s_ = srcs[q_] + (size_t)(kt) * 4096;                 \
                _Pragma("unroll")                                                          \
                for (int c_ = 0; c_ < 2; ++c_)                                             \
                    __builtin_amdgcn_global_load_lds(                                      \
                        (const __attribute__((address_space(1))) unsigned int*)(s_ + c_ * 2048 + tid * 8), \
                        (__attribute__((address_space(3))) unsigned int*)&lds[buf][q_][c_ * 2048 + tid * 8], \
                        16, 0, 0);                                                         \
            }                                                                              \
        } while (0)

    GSTAGE(0, 0);
    for (int kt = 0; kt < 8; ++kt) {
        __syncthreads();                             // drains loads into buf cur
        const int cur = kt & 1;
        if (kt + 1 < 8) GSTAGE(cur ^ 1, kt + 1);
        #pragma unroll
        for (int ks = 0; ks < 2; ++ks) {
            bf16x8 ah[2], al[2], bh[2], bl[2];
            #pragma unroll
            for (int t = 0; t < 2; ++t) {
                const int m_ = mi + t * 16 + row;
                const int offa = m_ * 64 + (((ks * 4 + quad) ^ (m_ & 7)) * 8);
                ah[t] = *(const bf16x8*)&lds[cur][0][offa];
                al[t] = *(const bf16x8*)&lds[cur][1][offa];
                const int f_ = fi + t * 16 + row;
                const int offb = f_ * 64 + (((ks * 4 + quad) ^ (f_ & 7)) * 8);
                bh[t] = *(const bf16x8*)&lds[cur][2][offb];
                bl[t] = *(const bf16x8*)&lds[cur][3][offb];
            }
            #pragma unroll
            for (int mt = 0; mt < 2; ++mt)
                #pragma unroll
                for (int nt = 0; nt < 2; ++nt) {
                    acc[mt][nt] = __builtin_amdgcn_mfma_f32_16x16x32_bf16(ah[mt], bh[nt], acc[mt][nt], 0, 0, 0);
                    acc[mt][nt] = __builtin_amdgcn_mfma_f32_16x16x32_bf16(al[mt], bh[nt], acc[mt][nt], 0, 0, 0);
                    acc[mt][nt] = __builtin_amdgcn_mfma_f32_16x16x32_bf16(ah[mt], bl[nt], acc[mt][nt], 0, 0, 0);
                }
        }
    }
    #undef GSTAGE
    // ---- fused epilogue ----
    __syncthreads();
    float* ht = (float*)&lds[0][0][0];               // 64 x 68 f32 (17.4 KB, fits)
    #pragma unroll
    for (int mt = 0; mt < 2; ++mt)
        #pragma unroll
        for (int nt = 0; nt < 2; ++nt)
            #pragma unroll
            for (int r = 0; r < 4; ++r)
                ht[(mi + mt * 16 + quad * 4 + r) * 68 + fi + nt * 16 + row] = acc[mt][nt][r];
    __syncthreads();
    {   // s1/s2 (pre-scaled by log2e): thread t -> row t>>2, seg (t&3)*16
        const int rrow = tid >> 2, seg = (tid & 3) * 16;
        const float* ah = As + head * 128;
        float p1 = 0.f, p2 = 0.f;
        #pragma unroll
        for (int c = 0; c < 16; ++c) {
            float v = ht[rrow * 68 + seg + c];
            p1 += v * ah[seg + c];
            p2 += v * ah[64 + seg + c];
        }
        p1 += __shfl_xor(p1, 1); p1 += __shfl_xor(p1, 2);
        p2 += __shfl_xor(p2, 1); p2 += __shfl_xor(p2, 2);
        if ((tid & 3) == 0) {
            s1L[head * GN + i0 + rrow] = p1 * LOG2E;
            s2L[head * GN + i0 + rrow] = p2 * LOG2E;
        }
    }
    {   // swizzled image emit (hi only)
        const int f = tid >> 2;
        size_t base = ((size_t)head * 64 + itile) * 4096 + (size_t)f * 64;
        #pragma unroll
        for (int p = 0; p < 2; ++p) {
            int c = (tid & 3) * 2 + p;
            unsigned hp[4];
            #pragma unroll
            for (int pp = 0; pp < 4; ++pp)
                hp[pp] = hi_pack2(ht[(c * 8 + 2 * pp) * 68 + f], ht[(c * 8 + 2 * pp + 1) * 68 + f]);
            int off = (c ^ (f & 7)) * 8;
            *(uint4*)&imgh[base + off] = *(uint4*)hp;
        }
    }
}

// Fused masked-softmax attention; w HI-ONLY bf16 (den from the SAME rounded
// values), h image HI-ONLY. 256 thr = 4 waves x 16 rows, nt=4.
// KEY R14 change: s2/adj loads for the CURRENT tile are issued BEFORE
// STAGE(next), so their vmcnt wait does not drain the staging queue.
// grid (64 i-tiles, GNH*NCHUNK or NCHUNK).
template <int NCHUNK>
__global__ __launch_bounds__(256, 4) void attn10(const unsigned short* __restrict__ imgh,
                                                 const float* __restrict__ s1g,
                                                 const float* __restrict__ s2g,
                                                 const unsigned long long* __restrict__ adjb,
                                                 float* __restrict__ pO,
                                                 float* __restrict__ pd) {
    __shared__ __align__(16) unsigned short hb[2][4096];   // [buf][hi, swizzled 64x64]
    const int tid = threadIdx.x;
    const int lane = tid & 63, wv = tid >> 6;
    const int row = lane & 15, quad = lane >> 4;
    const int head = blockIdx.y / NCHUNK;
    const int chunk = blockIdx.y % NCHUNK;
    const int i0 = blockIdx.x * 64;
    const int jb = chunk * (GN / NCHUNK);
    const int njt = (GN / NCHUNK) / 64;
    const int jt0 = jb >> 6;
    const unsigned short* ih = imgh + (size_t)head * (64 * GN);
    const float* s2h = s2g + head * GN;
    const int gr = i0 + wv * 16 + row;
    const float s1v = s1g[head * GN + gr];
    const unsigned long long* adjr = adjb + (size_t)gr * 64 + jt0;

    f32x4 acc[4] = {};
    float den = 0.f;

    #define STAGE(buf, T)                                                                  \
        do {                                                                               \
            const unsigned short* gh_ = ih + (size_t)(T) * 4096;                           \
            _Pragma("unroll")                                                              \
            for (int c_ = 0; c_ < 2; ++c_)                                                 \
                __builtin_amdgcn_global_load_lds(                                          \
                    (const __attribute__((address_space(1))) unsigned int*)(gh_ + c_ * 2048 + tid * 8), \
                    (__attribute__((address_space(3))) unsigned int*)&hb[buf][c_ * 2048 + tid * 8],     \
                    16, 0, 0);                                                             \
        } while (0)

    STAGE(0, jt0);
    for (int jt = 0; jt < njt; ++jt) {
        __syncthreads();                             // drains loads into buf cur
        const int cur = jt & 1;
        const int j0 = jb + jt * 64;
        // ---- loads for the CURRENT tile, issued BEFORE next-tile staging ----
        const unsigned long long wd = adjr[jt];
        float4 sa0 = *(const float4*)&s2h[j0 + quad * 8];
        float4 sb0 = *(const float4*)&s2h[j0 + quad * 8 + 4];
        float4 sa1 = *(const float4*)&s2h[j0 + 32 + quad * 8];
        float4 sb1 = *(const float4*)&s2h[j0 + 32 + quad * 8 + 4];
        // ---- next-tile staging: newest in vmcnt queue, NOT drained by s2 waits
        if (jt + 1 < njt) STAGE(cur ^ 1, jt0 + jt + 1);
        #pragma unroll
        for (int ks = 0; ks < 2; ++ks) {
            const int kb = ks * 32 + quad * 8;
            const float s2v[8] = {ks ? sa1.x : sa0.x, ks ? sa1.y : sa0.y,
                                  ks ? sa1.z : sa0.z, ks ? sa1.w : sa0.w,
                                  ks ? sb1.x : sb0.x, ks ? sb1.y : sb0.y,
                                  ks ? sb1.z : sb0.z, ks ? sb1.w : sb0.w};
            const unsigned bits = (unsigned)(wd >> kb) & 0xFFu;
            union { unsigned u[4]; bf16x8 v; } hfr;
            #pragma unroll
            for (int p = 0; p < 4; ++p) {
                float m0 = (float)((bits >> (2 * p)) & 1u);
                float m1 = (float)((bits >> (2 * p + 1)) & 1u);
                float t0 = s1v + s2v[2 * p];
                float t1 = s1v + s2v[2 * p + 1];
                float w0 = FAST_EXP2(fmaxf(t0, 0.2f * t0)) * m0;
                float w1 = FAST_EXP2(fmaxf(t1, 0.2f * t1)) * m1;
                unsigned u0 = __float_as_uint(w0) + 0x8000u;
                unsigned u1 = __float_as_uint(w1) + 0x8000u;
                // denominator from the SAME rounded values the MFMA consumes
                den += __uint_as_float(u0 & 0xFFFF0000u) + __uint_as_float(u1 & 0xFFFF0000u);
                hfr.u[p] = FAST_PERM(u1, u0, 0x07060302u);
            }
            #pragma unroll
            for (int nt = 0; nt < 4; ++nt) {
                const int f = nt * 16 + row;
                const int off = f * 64 + (((ks * 4 + quad) ^ (f & 7)) * 8);
                bf16x8 bh = *(const bf16x8*)&hb[cur][off];
                acc[nt] = __builtin_amdgcn_mfma_f32_16x16x32_bf16(hfr.v, bh, acc[nt], 0, 0, 0);
            }
        }
    }
    #undef STAGE
    den += __shfl_xor(den, 16);
    den += __shfl_xor(den, 32);
    float* o = pO + (size_t)blockIdx.y * (GN * 64);
    #pragma unroll
    for (int r = 0; r < 4; ++r) {
        const int grow = i0 + wv * 16 + quad * 4 + r;
        #pragma unroll
        for (int nt = 0; nt < 4; ++nt)
            o[(size_t)grow * 64 + nt * 16 + row] = acc[nt][r];
    }
    if (lane < 16) pd[blockIdx.y * GN + i0 + wv * 16 + lane] = den;
}

// Fused zred + l2prep, 16 rows/block (256 blocks): combine 2-chunk L1
// partials -> z (LDS) -> h2 = z @ W_out -> s1b/s2b + hi-only image.
__global__ __launch_bounds__(256) void mid(const float* __restrict__ pO,
                                           const float* __restrict__ pd,
                                           const float* __restrict__ Wo,
                                           const float* __restrict__ ao,
                                           unsigned short* __restrict__ img2h,
                                           float* __restrict__ s1bL,
                                           float* __restrict__ s2bL) {
    __shared__ __align__(16) float zt[16][68];
    __shared__ float Wl[64 * 57];
    __shared__ float invd[8][16];
    const int tid = threadIdx.x;
    const int i0 = blockIdx.x * 16;
    for (int idx = tid; idx < 64 * 56; idx += 256) {
        int k = idx / 56, c = idx - k * 56;
        Wl[k * 57 + c] = Wo[idx];
    }
    if (tid < 128) {
        int hd = tid >> 4, r = tid & 15;
        invd[hd][r] = 1.f / (pd[(2 * hd) * GN + i0 + r] + pd[(2 * hd + 1) * GN + i0 + r]);
    }
    __syncthreads();
    #pragma unroll
    for (int it = 0; it < 4; ++it) {                 // z fill: 16x64 elems
        int e = it * 256 + tid;
        int r = e >> 6, f = e & 63;
        size_t base = (size_t)(i0 + r) * 64 + f;
        float s = 0.f;
        #pragma unroll
        for (int hd = 0; hd < GNH; ++hd) {
            float o = pO[(size_t)(2 * hd) * (GN * 64) + base] +
                      pO[(size_t)(2 * hd + 1) * (GN * 64) + base];
            float v = o * invd[hd][r];
            s += v > 0.f ? v : FAST_EXP2(v * LOG2E) - 1.f;
        }
        zt[r][f] = s * 0.125f;
    }
    __syncthreads();
    const int rrow = tid >> 4, cseg = (tid & 15) * 4;
    float hreg[4] = {0.f, 0.f, 0.f, 0.f};
    for (int k0 = 0; k0 < 64; k0 += 4) {
        float4 zv = *(const float4*)&zt[rrow][k0];
        #pragma unroll
        for (int c = 0; c < 4; ++c) {
            int col = cseg + c;
            if (col < 56)
                hreg[c] += zv.x * Wl[k0 * 57 + col] + zv.y * Wl[(k0 + 1) * 57 + col] +
                           zv.z * Wl[(k0 + 2) * 57 + col] + zv.w * Wl[(k0 + 3) * 57 + col];
        }
    }
    {   // s1b/s2b (pre-scaled by log2e); reduce across 16 threads of the row
        float p1 = 0.f, p2 = 0.f;
        #pragma unroll
        for (int c = 0; c < 4; ++c) {
            int col = cseg + c;
            if (col < 56) {
                p1 += hreg[c] * ao[col];
                p2 += hreg[c] * ao[56 + col];
            }
        }
        p1 += __shfl_xor(p1, 1); p1 += __shfl_xor(p1, 2);
        p1 += __shfl_xor(p1, 4); p1 += __shfl_xor(p1, 8);
        p2 += __shfl_xor(p2, 1); p2 += __shfl_xor(p2, 2);
        p2 += __shfl_xor(p2, 4); p2 += __shfl_xor(p2, 8);
        if ((tid & 15) == 0) {
            s1bL[i0 + rrow] = p1 * LOG2E;
            s2bL[i0 + rrow] = p2 * LOG2E;
        }
    }
    __syncthreads();
    #pragma unroll
    for (int c = 0; c < 4; ++c) zt[rrow][cseg + c] = (cseg + c < 56) ? hreg[c] : 0.f;
    __syncthreads();
    if (tid < 128) {                                 // img emit: 64 f x 2 c-units
        const int jt = i0 >> 6;
        const int cbase = (i0 & 63) >> 3;
        const int f = tid >> 1, c = cbase + (tid & 1);
        const int lr = (tid & 1) * 8;
        unsigned hp[4];
        #pragma unroll
        for (int pp = 0; pp < 4; ++pp)
            hp[pp] = hi_pack2(zt[lr + 2 * pp][f], zt[lr + 2 * pp + 1][f]);
        size_t base = (size_t)jt * 4096 + f * 64 + ((c ^ (f & 7)) * 8);
        *(uint4*)&img2h[base] = *(uint4*)hp;
    }
}

// combine 16 j-chunk partials, /denom, elu, softmax(56) -> out
__global__ __launch_bounds__(256) void fink2(const float* __restrict__ pO,
                                             const float* __restrict__ pd,
                                             float* __restrict__ out) {
    const int lane = threadIdx.x & 63;
    const int w = threadIdx.x >> 6;
    const int i = blockIdx.x * 4 + w;
    float o = 0.f, d = 0.f;
    #pragma unroll
    for (int c = 0; c < 16; ++c) d += pd[c * GN + i];
    if (lane < 56) {
        #pragma unroll
        for (int c = 0; c < 16; ++c) o += pO[(size_t)c * (GN * 64) + (size_t)i * 64 + lane];
    }
    float v = -1e30f;
    if (lane < 56) {
        float t = o / d;
        v = t > 0.f ? t : expm1f(t);
    }
    float m = v;
    #pragma unroll
    for (int off = 32; off; off >>= 1) m = fmaxf(m, __shfl_down(m, off));
    m = __shfl(m, 0);
    float p = (lane < 56) ? __expf(v - m) : 0.f;
    float s = p;
    #pragma unroll
    for (int off = 32; off; off >>= 1) s += __shfl_down(s, off);
    s = __shfl(s, 0);
    if (lane < 56) out[(size_t)i * 56 + lane] = p / s;
}

extern "C" void kernel_launch(void* const* d_in, const int* in_sizes, int n_in,
                              void* d_out, int out_size, void* d_ws, size_t ws_size,
                              hipStream_t stream) {
    const float* x    = (const float*)d_in[0];
    const int*   adj  = (const int*)d_in[1];
    const float* Ws   = (const float*)d_in[2];
    const float* As   = (const float*)d_in[3];
    const float* Wo   = (const float*)d_in[4];
    const float* ao   = (const float*)d_in[5];
    float* out = (float*)d_out;

    char* ws = (char*)d_ws;
    unsigned long long* adjb = (unsigned long long*)(ws + 0);           // 2 MB
    unsigned short* img1h = (unsigned short*)(ws + 2097152);            // 4 MB
    float* pO    = (float*)(ws + 6291456);                              // 16 MB (16 slices)
    unsigned short* x_hi = (unsigned short*)(ws + 6291456);             // 4 MB (alias pO, pre-gemm)
    unsigned short* x_lo = (unsigned short*)(ws + 10485760);            // 4 MB (alias pO, pre-gemm)
    float* pd    = (float*)(ws + 23068672);                             // 256 KB (shared L1/L2)
    float* s1L   = (float*)(ws + 23330816);                             // 128 KB
    float* s2L   = (float*)(ws + 23461888);                             // 128 KB
    float* s1bL  = (float*)(ws + 23592960);                             // 16 KB
    float* s2bL  = (float*)(ws + 23609344);                             // 16 KB
    unsigned short* img2h = (unsigned short*)(ws + 23625728);           // 512 KB
    unsigned short* WT_hi = (unsigned short*)(ws + 24150016);           // 512 KB
    unsigned short* WT_lo = (unsigned short*)(ws + 24674304);           // 512 KB
    // total 25198592 B ~= 24 MB

    prep<<<17472, 256, 0, stream>>>(adj, x, Ws, adjb, x_hi, x_lo, WT_hi, WT_lo);
    gemm_fused<<<dim3(8, 64), 256, 0, stream>>>(x_hi, x_lo, WT_hi, WT_lo, As,
                                                img1h, s1L, s2L);
    attn10<2><<<dim3(64, 16), 256, 0, stream>>>(img1h, s1L, s2L, adjb, pO, pd);
    mid<<<256, 256, 0, stream>>>(pO, pd, Wo, ao, img2h, s1bL, s2bL);
    attn10<16><<<dim3(64, 16), 256, 0, stream>>>(img2h, s1bL, s2bL, adjb, pO, pd);
    fink2<<<1024, 256, 0, stream>>>(pO, pd, out);
}

// Round 15
// 214.511 us; speedup vs baseline: 1.0570x; 1.0141x over previous
//
#include <hip/hip_runtime.h>
#include <hip/hip_bf16.h>
#include <math.h>

// GAT forward, N=4096, nfeat=512, nhid=64, nheads=8, nout=56, f32 in/out.
// R15 vs R14 (R14: 217.5us; attn-L1 65.5 w/ vmcnt-decoupled prefetch; the
// OTHER ~135us is prep/gemm/mid/fink2, with gemm still doing a 3-product
// split feeding an h-image that attention rounds to bf16-hi anyway):
//  - gemm_fused: PURE bf16 hi-only (x_hi @ W_hi, 1 MFMA product, was 3).
//    Staging halves (16KB/tile), LDS 32KB -> 4 blk/CU (was 2), MFMA/block
//    192 -> 64. h rel err ~3e-3, averaged ~7e-5 in O (R12 precedent: output
//    absmax insensitive to operand-split precision).
//  - prep: conv_x / conv_wt emit hi image only (half the bytes).
//  - attn10 / mid / fink2 byte-identical to R14.
// Workspace ~25 MB.

#define GN 4096
#define GNH 8
#define LOG2E 1.4426950408889634f

typedef __bf16 bf16x8 __attribute__((ext_vector_type(8)));
typedef float f32x4 __attribute__((ext_vector_type(4)));

#if defined(__has_builtin)
#if __has_builtin(__builtin_amdgcn_exp2f)
#define FAST_EXP2(x) __builtin_amdgcn_exp2f(x)
#endif
#if __has_builtin(__builtin_amdgcn_perm)
#define FAST_PERM(a, b, s) __builtin_amdgcn_perm((a), (b), (s))
#endif
#endif
#ifndef FAST_EXP2
#define FAST_EXP2(x) __expf((x)*0.6931471805599453f)
#endif
#ifndef FAST_PERM
__device__ inline unsigned FAST_PERM(unsigned a, unsigned b, unsigned) {
    return (a & 0xFFFF0000u) | (b >> 16);
}
#endif

// round-half-up hi only, packed pair: low 16 = v0's bf16, high 16 = v1's
__device__ inline unsigned hi_pack2(float w0, float w1) {
    unsigned u0 = __float_as_uint(w0) + 0x8000u;
    unsigned u1 = __float_as_uint(w1) + 0x8000u;
    return FAST_PERM(u1, u0, 0x07060302u);
}

// Fused prep:
//  [0,16384)      pack_adj  (bitmask)
//  [16384,17408)  conv_x    -> swizzled x image (hi only), tiles [itile*8+kt]
//  [17408,17472)  conv_wt   -> swizzled W^T image (hi only), tiles [head*8+kt]
// Image unit (m, c) at shorts offset m*64 + ((c^(m&7))*8), elems k = c*8+q.
__global__ __launch_bounds__(256) void prep(const int* __restrict__ adj,
                                            const float* __restrict__ x,
                                            const float* __restrict__ Ws,
                                            unsigned long long* __restrict__ adjb,
                                            unsigned short* __restrict__ xh,
                                            unsigned short* __restrict__ wth) {
    const int b = blockIdx.x;
    const int tid = threadIdx.x;
    if (b < 16384) {
        const int wv = tid >> 6, lane = tid & 63;
        const size_t ebase = ((size_t)b * 4 + wv) * 256;
        unsigned long long m[4];
        #pragma unroll
        for (int e = 0; e < 4; ++e)
            m[e] = __ballot(adj[ebase + e * 64 + lane] > 0);
        if (lane == 0) {
            #pragma unroll
            for (int e = 0; e < 4; ++e) adjb[(ebase >> 6) + e] = m[e];
        }
    } else if (b < 17408) {
        int gid = (b - 16384) * 256 + tid;           // over 4096 rows x 64 units
        int i = gid >> 6, c64 = gid & 63;
        const float* xp = x + (size_t)i * 512 + c64 * 8;
        float4 a = *(const float4*)xp;
        float4 v = *(const float4*)(xp + 4);
        unsigned hp[4];
        hp[0] = hi_pack2(a.x, a.y);
        hp[1] = hi_pack2(a.z, a.w);
        hp[2] = hi_pack2(v.x, v.y);
        hp[3] = hi_pack2(v.z, v.w);
        int il = i & 63, kt = c64 >> 3, c = c64 & 7;
        size_t base = ((size_t)(i >> 6) * 8 + kt) * 4096 + il * 64 + ((c ^ (il & 7)) * 8);
        *(uint4*)&xh[base] = *(uint4*)hp;
    } else {
        __shared__ float t[64][65];
        int b2 = b - 17408;                          // head*8 + kt
        int head = b2 >> 3, k0 = (b2 & 7) * 64;
        #pragma unroll
        for (int it = 0; it < 4; ++it) {
            int e = (tid + it * 256) * 4;            // over 64k x 64f
            int kl = e >> 6, f4 = e & 63;
            float4 v = *(const float4*)&Ws[((size_t)head * 512 + k0 + kl) * 64 + f4];
            t[f4 + 0][kl] = v.x; t[f4 + 1][kl] = v.y;
            t[f4 + 2][kl] = v.z; t[f4 + 3][kl] = v.w;
        }
        __syncthreads();
        int f = tid >> 2;
        #pragma unroll
        for (int p = 0; p < 2; ++p) {
            int c = (tid & 3) * 2 + p;
            unsigned hp[4];
            #pragma unroll
            for (int pp = 0; pp < 4; ++pp)
                hp[pp] = hi_pack2(t[f][c * 8 + 2 * pp], t[f][c * 8 + 2 * pp + 1]);
            size_t base = (size_t)b2 * 4096 + f * 64 + ((c ^ (f & 7)) * 8);
            *(uint4*)&wth[base] = *(uint4*)hp;
        }
    }
}

// h = x_hi @ W_hi (single bf16 product), m97-style staging, 4 blk/CU.
// Epilogue emits hi-only swizzled h image + s1L/s2L. grid (8 heads, 64 itiles).
__global__ __launch_bounds__(256) void gemm_fused(const unsigned short* __restrict__ xh,
                                                  const unsigned short* __restrict__ wth,
                                                  const float* __restrict__ As,
                                                  unsigned short* __restrict__ imgh,
                                                  float* __restrict__ s1L,
                                                  float* __restrict__ s2L) {
    __shared__ __align__(16) unsigned short lds[2][2][4096];  // 32 KB: [buf][x,w]
    const int tid = threadIdx.x;
    const int head = blockIdx.x;
    const int itile = blockIdx.y;
    const int i0 = itile * 64;
    const unsigned short* srcs[2] = {xh + (size_t)itile * 8 * 4096,
                                     wth + (size_t)head * 8 * 4096};
    const int lane = tid & 63, wv_ = tid >> 6;
    const int mi = (wv_ & 1) * 32, fi = (wv_ >> 1) * 32;
    const int row = lane & 15, quad = lane >> 4;
    f32x4 acc[2][2] = {};

    #define GSTAGE(buf, kt)                                                                \
        do {                                                                               \
            _Pragma("unroll")                                                              \
            for (int q_ = 0; q_ < 2; ++q_) {                                               \
                const unsigned short* s_ = srcs[q_] + (size_t)(kt) * 4096;                 \
                _Pragma("unroll")                                                          \
                for (int c_ = 0; c_ < 2; ++c_)                                             \
                    __builtin_amdgcn_global_load_lds(                                      \
                        (const __attribute__((address_space(1))) unsigned int*)(s_ + c_ * 2048 + tid * 8), \
                        (__attribute__((address_space(3))) unsigned int*)&lds[buf][q_][c_ * 2048 + tid * 8], \
                        16, 0, 0);                                                         \
            }                                                                              \
        } while (0)

    GSTAGE(0, 0);
    for (int kt = 0; kt < 8; ++kt) {
        __syncthreads();                             // drains loads into buf cur
        const int cur = kt & 1;
        if (kt + 1 < 8) GSTAGE(cur ^ 1, kt + 1);
        #pragma unroll
        for (int ks = 0; ks < 2; ++ks) {
            bf16x8 ah[2], bh[2];
            #pragma unroll
            for (int t = 0; t < 2; ++t) {
                const int m_ = mi + t * 16 + row;
                const int offa = m_ * 64 + (((ks * 4 + quad) ^ (m_ & 7)) * 8);
                ah[t] = *(const bf16x8*)&lds[cur][0][offa];
                const int f_ = fi + t * 16 + row;
                const int offb = f_ * 64 + (((ks * 4 + quad) ^ (f_ & 7)) * 8);
                bh[t] = *(const bf16x8*)&lds[cur][1][offb];
            }
            #pragma unroll
            for (int mt = 0; mt < 2; ++mt)
                #pragma unroll
                for (int nt = 0; nt < 2; ++nt)
                    acc[mt][nt] = __builtin_amdgcn_mfma_f32_16x16x32_bf16(ah[mt], bh[nt], acc[mt][nt], 0, 0, 0);
        }
    }
    #undef GSTAGE
    // ---- fused epilogue ----
    __syncthreads();
    float* ht = (float*)&lds[0][0][0];               // 64 x 68 f32 (17.4 KB <= 32 KB)
    #pragma unroll
    for (int mt = 0; mt < 2; ++mt)
        #pragma unroll
        for (int nt = 0; nt < 2; ++nt)
            #pragma unroll
            for (int r = 0; r < 4; ++r)
                ht[(mi + mt * 16 + quad * 4 + r) * 68 + fi + nt * 16 + row] = acc[mt][nt][r];
    __syncthreads();
    {   // s1/s2 (pre-scaled by log2e): thread t -> row t>>2, seg (t&3)*16
        const int rrow = tid >> 2, seg = (tid & 3) * 16;
        const float* ah = As + head * 128;
        float p1 = 0.f, p2 = 0.f;
        #pragma unroll
        for (int c = 0; c < 16; ++c) {
            float v = ht[rrow * 68 + seg + c];
            p1 += v * ah[seg + c];
            p2 += v * ah[64 + seg + c];
        }
        p1 += __shfl_xor(p1, 1); p1 += __shfl_xor(p1, 2);
        p2 += __shfl_xor(p2, 1); p2 += __shfl_xor(p2, 2);
        if ((tid & 3) == 0) {
            s1L[head * GN + i0 + rrow] = p1 * LOG2E;
            s2L[head * GN + i0 + rrow] = p2 * LOG2E;
        }
    }
    {   // swizzled image emit (hi only)
        const int f = tid >> 2;
        size_t base = ((size_t)head * 64 + itile) * 4096 + (size_t)f * 64;
        #pragma unroll
        for (int p = 0; p < 2; ++p) {
            int c = (tid & 3) * 2 + p;
            unsigned hp[4];
            #pragma unroll
            for (int pp = 0; pp < 4; ++pp)
                hp[pp] = hi_pack2(ht[(c * 8 + 2 * pp) * 68 + f], ht[(c * 8 + 2 * pp + 1) * 68 + f]);
            int off = (c ^ (f & 7)) * 8;
            *(uint4*)&imgh[base + off] = *(uint4*)hp;
        }
    }
}

// Fused masked-softmax attention; w HI-ONLY bf16 (den from the SAME rounded
// values), h image HI-ONLY. 256 thr = 4 waves x 16 rows, nt=4.
// s2/adj loads issued BEFORE STAGE(next) (vmcnt decoupling, R14-proven).
// grid (64 i-tiles, GNH*NCHUNK or NCHUNK).
template <int NCHUNK>
__global__ __launch_bounds__(256, 4) void attn10(const unsigned short* __restrict__ imgh,
                                                 const float* __restrict__ s1g,
                                                 const float* __restrict__ s2g,
                                                 const unsigned long long* __restrict__ adjb,
                                                 float* __restrict__ pO,
                                                 float* __restrict__ pd) {
    __shared__ __align__(16) unsigned short hb[2][4096];   // [buf][hi, swizzled 64x64]
    const int tid = threadIdx.x;
    const int lane = tid & 63, wv = tid >> 6;
    const int row = lane & 15, quad = lane >> 4;
    const int head = blockIdx.y / NCHUNK;
    const int chunk = blockIdx.y % NCHUNK;
    const int i0 = blockIdx.x * 64;
    const int jb = chunk * (GN / NCHUNK);
    const int njt = (GN / NCHUNK) / 64;
    const int jt0 = jb >> 6;
    const unsigned short* ih = imgh + (size_t)head * (64 * GN);
    const float* s2h = s2g + head * GN;
    const int gr = i0 + wv * 16 + row;
    const float s1v = s1g[head * GN + gr];
    const unsigned long long* adjr = adjb + (size_t)gr * 64 + jt0;

    f32x4 acc[4] = {};
    float den = 0.f;

    #define STAGE(buf, T)                                                                  \
        do {                                                                               \
            const unsigned short* gh_ = ih + (size_t)(T) * 4096;                           \
            _Pragma("unroll")                                                              \
            for (int c_ = 0; c_ < 2; ++c_)                                                 \
                __builtin_amdgcn_global_load_lds(                                          \
                    (const __attribute__((address_space(1))) unsigned int*)(gh_ + c_ * 2048 + tid * 8), \
                    (__attribute__((address_space(3))) unsigned int*)&hb[buf][c_ * 2048 + tid * 8],     \
                    16, 0, 0);                                                             \
        } while (0)

    STAGE(0, jt0);
    for (int jt = 0; jt < njt; ++jt) {
        __syncthreads();                             // drains loads into buf cur
        const int cur = jt & 1;
        const int j0 = jb + jt * 64;
        // ---- loads for the CURRENT tile, issued BEFORE next-tile staging ----
        const unsigned long long wd = adjr[jt];
        float4 sa0 = *(const float4*)&s2h[j0 + quad * 8];
        float4 sb0 = *(const float4*)&s2h[j0 + quad * 8 + 4];
        float4 sa1 = *(const float4*)&s2h[j0 + 32 + quad * 8];
        float4 sb1 = *(const float4*)&s2h[j0 + 32 + quad * 8 + 4];
        // ---- next-tile staging: newest in vmcnt queue, NOT drained by s2 waits
        if (jt + 1 < njt) STAGE(cur ^ 1, jt0 + jt + 1);
        #pragma unroll
        for (int ks = 0; ks < 2; ++ks) {
            const int kb = ks * 32 + quad * 8;
            const float s2v[8] = {ks ? sa1.x : sa0.x, ks ? sa1.y : sa0.y,
                                  ks ? sa1.z : sa0.z, ks ? sa1.w : sa0.w,
                                  ks ? sb1.x : sb0.x, ks ? sb1.y : sb0.y,
                                  ks ? sb1.z : sb0.z, ks ? sb1.w : sb0.w};
            const unsigned bits = (unsigned)(wd >> kb) & 0xFFu;
            union { unsigned u[4]; bf16x8 v; } hfr;
            #pragma unroll
            for (int p = 0; p < 4; ++p) {
                float m0 = (float)((bits >> (2 * p)) & 1u);
                float m1 = (float)((bits >> (2 * p + 1)) & 1u);
                float t0 = s1v + s2v[2 * p];
                float t1 = s1v + s2v[2 * p + 1];
                float w0 = FAST_EXP2(fmaxf(t0, 0.2f * t0)) * m0;
                float w1 = FAST_EXP2(fmaxf(t1, 0.2f * t1)) * m1;
                unsigned u0 = __float_as_uint(w0) + 0x8000u;
                unsigned u1 = __float_as_uint(w1) + 0x8000u;
                // denominator from the SAME rounded values the MFMA consumes
                den += __uint_as_float(u0 & 0xFFFF0000u) + __uint_as_float(u1 & 0xFFFF0000u);
                hfr.u[p] = FAST_PERM(u1, u0, 0x07060302u);
            }
            #pragma unroll
            for (int nt = 0; nt < 4; ++nt) {
                const int f = nt * 16 + row;
                const int off = f * 64 + (((ks * 4 + quad) ^ (f & 7)) * 8);
                bf16x8 bh = *(const bf16x8*)&hb[cur][off];
                acc[nt] = __builtin_amdgcn_mfma_f32_16x16x32_bf16(hfr.v, bh, acc[nt], 0, 0, 0);
            }
        }
    }
    #undef STAGE
    den += __shfl_xor(den, 16);
    den += __shfl_xor(den, 32);
    float* o = pO + (size_t)blockIdx.y * (GN * 64);
    #pragma unroll
    for (int r = 0; r < 4; ++r) {
        const int grow = i0 + wv * 16 + quad * 4 + r;
        #pragma unroll
        for (int nt = 0; nt < 4; ++nt)
            o[(size_t)grow * 64 + nt * 16 + row] = acc[nt][r];
    }
    if (lane < 16) pd[blockIdx.y * GN + i0 + wv * 16 + lane] = den;
}

// Fused zred + l2prep, 16 rows/block (256 blocks): combine 2-chunk L1
// partials -> z (LDS) -> h2 = z @ W_out -> s1b/s2b + hi-only image.
__global__ __launch_bounds__(256) void mid(const float* __restrict__ pO,
                                           const float* __restrict__ pd,
                                           const float* __restrict__ Wo,
                                           const float* __restrict__ ao,
                                           unsigned short* __restrict__ img2h,
                                           float* __restrict__ s1bL,
                                           float* __restrict__ s2bL) {
    __shared__ __align__(16) float zt[16][68];
    __shared__ float Wl[64 * 57];
    __shared__ float invd[8][16];
    const int tid = threadIdx.x;
    const int i0 = blockIdx.x * 16;
    for (int idx = tid; idx < 64 * 56; idx += 256) {
        int k = idx / 56, c = idx - k * 56;
        Wl[k * 57 + c] = Wo[idx];
    }
    if (tid < 128) {
        int hd = tid >> 4, r = tid & 15;
        invd[hd][r] = 1.f / (pd[(2 * hd) * GN + i0 + r] + pd[(2 * hd + 1) * GN + i0 + r]);
    }
    __syncthreads();
    #pragma unroll
    for (int it = 0; it < 4; ++it) {                 // z fill: 16x64 elems
        int e = it * 256 + tid;
        int r = e >> 6, f = e & 63;
        size_t base = (size_t)(i0 + r) * 64 + f;
        float s = 0.f;
        #pragma unroll
        for (int hd = 0; hd < GNH; ++hd) {
            float o = pO[(size_t)(2 * hd) * (GN * 64) + base] +
                      pO[(size_t)(2 * hd + 1) * (GN * 64) + base];
            float v = o * invd[hd][r];
            s += v > 0.f ? v : FAST_EXP2(v * LOG2E) - 1.f;
        }
        zt[r][f] = s * 0.125f;
    }
    __syncthreads();
    const int rrow = tid >> 4, cseg = (tid & 15) * 4;
    float hreg[4] = {0.f, 0.f, 0.f, 0.f};
    for (int k0 = 0; k0 < 64; k0 += 4) {
        float4 zv = *(const float4*)&zt[rrow][k0];
        #pragma unroll
        for (int c = 0; c < 4; ++c) {
            int col = cseg + c;
            if (col < 56)
                hreg[c] += zv.x * Wl[k0 * 57 + col] + zv.y * Wl[(k0 + 1) * 57 + col] +
                           zv.z * Wl[(k0 + 2) * 57 + col] + zv.w * Wl[(k0 + 3) * 57 + col];
        }
    }
    {   // s1b/s2b (pre-scaled by log2e); reduce across 16 threads of the row
        float p1 = 0.f, p2 = 0.f;
        #pragma unroll
        for (int c = 0; c < 4; ++c) {
            int col = cseg + c;
            if (col < 56) {
                p1 += hreg[c] * ao[col];
                p2 += hreg[c] * ao[56 + col];
            }
        }
        p1 += __shfl_xor(p1, 1); p1 += __shfl_xor(p1, 2);
        p1 += __shfl_xor(p1, 4); p1 += __shfl_xor(p1, 8);
        p2 += __shfl_xor(p2, 1); p2 += __shfl_xor(p2, 2);
        p2 += __shfl_xor(p2, 4); p2 += __shfl_xor(p2, 8);
        if ((tid & 15) == 0) {
            s1bL[i0 + rrow] = p1 * LOG2E;
            s2bL[i0 + rrow] = p2 * LOG2E;
        }
    }
    __syncthreads();
    #pragma unroll
    for (int c = 0; c < 4; ++c) zt[rrow][cseg + c] = (cseg + c < 56) ? hreg[c] : 0.f;
    __syncthreads();
    if (tid < 128) {                                 // img emit: 64 f x 2 c-units
        const int jt = i0 >> 6;
        const int cbase = (i0 & 63) >> 3;
        const int f = tid >> 1, c = cbase + (tid & 1);
        const int lr = (tid & 1) * 8;
        unsigned hp[4];
        #pragma unroll
        for (int pp = 0; pp < 4; ++pp)
            hp[pp] = hi_pack2(zt[lr + 2 * pp][f], zt[lr + 2 * pp + 1][f]);
        size_t base = (size_t)jt * 4096 + f * 64 + ((c ^ (f & 7)) * 8);
        *(uint4*)&img2h[base] = *(uint4*)hp;
    }
}

// combine 16 j-chunk partials, /denom, elu, softmax(56) -> out
__global__ __launch_bounds__(256) void fink2(const float* __restrict__ pO,
                                             const float* __restrict__ pd,
                                             float* __restrict__ out) {
    const int lane = threadIdx.x & 63;
    const int w = threadIdx.x >> 6;
    const int i = blockIdx.x * 4 + w;
    float o = 0.f, d = 0.f;
    #pragma unroll
    for (int c = 0; c < 16; ++c) d += pd[c * GN + i];
    if (lane < 56) {
        #pragma unroll
        for (int c = 0; c < 16; ++c) o += pO[(size_t)c * (GN * 64) + (size_t)i * 64 + lane];
    }
    float v = -1e30f;
    if (lane < 56) {
        float t = o / d;
        v = t > 0.f ? t : expm1f(t);
    }
    float m = v;
    #pragma unroll
    for (int off = 32; off; off >>= 1) m = fmaxf(m, __shfl_down(m, off));
    m = __shfl(m, 0);
    float p = (lane < 56) ? __expf(v - m) : 0.f;
    float s = p;
    #pragma unroll
    for (int off = 32; off; off >>= 1) s += __shfl_down(s, off);
    s = __shfl(s, 0);
    if (lane < 56) out[(size_t)i * 56 + lane] = p / s;
}

extern "C" void kernel_launch(void* const* d_in, const int* in_sizes, int n_in,
                              void* d_out, int out_size, void* d_ws, size_t ws_size,
                              hipStream_t stream) {
    const float* x    = (const float*)d_in[0];
    const int*   adj  = (const int*)d_in[1];
    const float* Ws   = (const float*)d_in[2];
    const float* As   = (const float*)d_in[3];
    const float* Wo   = (const float*)d_in[4];
    const float* ao   = (const float*)d_in[5];
    float* out = (float*)d_out;

    char* ws = (char*)d_ws;
    unsigned long long* adjb = (unsigned long long*)(ws + 0);           // 2 MB
    unsigned short* img1h = (unsigned short*)(ws + 2097152);            // 4 MB
    float* pO    = (float*)(ws + 6291456);                              // 16 MB (16 slices)
    unsigned short* x_hi = (unsigned short*)(ws + 6291456);             // 4 MB (alias pO, pre-gemm)
    float* pd    = (float*)(ws + 23068672);                             // 256 KB (shared L1/L2)
    float* s1L   = (float*)(ws + 23330816);                             // 128 KB
    float* s2L   = (float*)(ws + 23461888);                             // 128 KB
    float* s1bL  = (float*)(ws + 23592960);                             // 16 KB
    float* s2bL  = (float*)(ws + 23609344);                             // 16 KB
    unsigned short* img2h = (unsigned short*)(ws + 23625728);           // 512 KB
    unsigned short* WT_hi = (unsigned short*)(ws + 24150016);           // 512 KB
    // total ~24 MB

    prep<<<17472, 256, 0, stream>>>(adj, x, Ws, adjb, x_hi, WT_hi);
    gemm_fused<<<dim3(8, 64), 256, 0, stream>>>(x_hi, WT_hi, As, img1h, s1L, s2L);
    attn10<2><<<dim3(64, 16), 256, 0, stream>>>(img1h, s1L, s2L, adjb, pO, pd);
    mid<<<256, 256, 0, stream>>>(pO, pd, Wo, ao, img2h, s1bL, s2bL);
    attn10<16><<<dim3(64, 16), 256, 0, stream>>>(img2h, s1bL, s2bL, adjb, pO, pd);
    fink2<<<1024, 256, 0, stream>>>(pO, pd, out);
}